// Round 1
// 811.481 us; speedup vs baseline: 1.1039x; 1.1039x over previous
//
#include <hip/hip_runtime.h>
#include <hip/hip_bf16.h>

// GCN 2-layer forward.
// R1: CSR + deterministic register aggregation; fused bias1+relu+GEMM2; fused output.
// R2: GEMM1 on bf16 MFMA (16x16x32, 128x128 tile).
// R3: pre-converted bf16 operands; m97-style global_load_lds staging both tiles.
// R4: parallel 3-phase scan; vectorized cvt; pre-scaled h1/h2; branch-free gathers.
// R5: DELETED cvt_kernel + xb buffer. GEMM1 reads f32 x directly and converts
//     f32->bf16 in the A-staging path (reg-staged, coalesced 2-row x 128B dword
//     loads); BN=256 (single column pass) so x is read exactly once. Pipeline
//     A-side traffic 719 MB -> 287 MB. B side stays global_load_lds (bf16 W1T).

#define N_NODES_   50000
#define NB_ROWS_   50048   // N_NODES_ rounded up to 64/128
#define N_EDGES_   1600000
#define N_FEAT_    1433
#define K_PAD_     1440
#define HIDDEN_    256
#define N_CLASSES_ 7
#define NPART_     ((N_NODES_ + 255) / 256)   // 196 scan partials

typedef __attribute__((ext_vector_type(8))) short short8;
typedef __attribute__((ext_vector_type(8))) unsigned short ushort8;
typedef __attribute__((ext_vector_type(4))) float f32x4;
typedef unsigned int u32;
typedef unsigned short u16;

__device__ __forceinline__ u16 f2bf(float f) {
    __hip_bfloat16 h = __float2bfloat16(f);   // RNE
    return *(u16*)&h;
}
__device__ __forceinline__ float bf2f(u16 u) {
    return __uint_as_float((u32)u << 16);
}
__device__ __forceinline__ void global_to_lds16(const void* g, void* l) {
    __builtin_amdgcn_global_load_lds(
        (const __attribute__((address_space(1))) u32*)g,
        (__attribute__((address_space(3))) u32*)l, 16, 0, 0);
}

// ---------------- degree histogram / norm ----------------
__global__ void deg_kernel(const int* __restrict__ dst, int* __restrict__ deg) {
    int i = blockIdx.x * blockDim.x + threadIdx.x;
    if (i < N_EDGES_) atomicAdd(&deg[dst[i]], 1);
}

__global__ void dinv_kernel(const int* __restrict__ deg, float* __restrict__ dinv) {
    int i = blockIdx.x * blockDim.x + threadIdx.x;
    if (i < N_NODES_) dinv[i] = rsqrtf((float)(deg[i] + 1));  // +1 self-loop
}

// ---------------- parallel scan: deg -> row_ptr/cursor ----------------
__global__ __launch_bounds__(256) void scan1_kernel(const int* __restrict__ deg,
                                                    int* __restrict__ partial) {
    __shared__ int ws[4];
    int t = threadIdx.x, b = blockIdx.x;
    int idx = b * 256 + t;
    int v = (idx < N_NODES_) ? deg[idx] : 0;
    #pragma unroll
    for (int off = 32; off > 0; off >>= 1) v += __shfl_down(v, off, 64);
    if ((t & 63) == 0) ws[t >> 6] = v;
    __syncthreads();
    if (t == 0) partial[b] = ws[0] + ws[1] + ws[2] + ws[3];
}

__global__ __launch_bounds__(256) void scan2_kernel(int* __restrict__ partial,
                                                    int* __restrict__ blk_off) {
    __shared__ int sh[256];
    int t = threadIdx.x;
    int v = (t < NPART_) ? partial[t] : 0;
    sh[t] = v;
    __syncthreads();
    #pragma unroll
    for (int off = 1; off < 256; off <<= 1) {
        int a = (t >= off) ? sh[t - off] : 0;
        __syncthreads();
        sh[t] += a;
        __syncthreads();
    }
    if (t < NPART_) blk_off[t] = sh[t] - v;  // exclusive
}

__global__ __launch_bounds__(256) void scan3_kernel(const int* __restrict__ deg,
                                                    const int* __restrict__ blk_off,
                                                    int* __restrict__ row_ptr,
                                                    int* __restrict__ cursor) {
    __shared__ int sh[256];
    int t = threadIdx.x, b = blockIdx.x;
    int idx = b * 256 + t;
    int v = (idx < N_NODES_) ? deg[idx] : 0;
    sh[t] = v;
    __syncthreads();
    #pragma unroll
    for (int off = 1; off < 256; off <<= 1) {
        int a = (t >= off) ? sh[t - off] : 0;
        __syncthreads();
        sh[t] += a;
        __syncthreads();
    }
    if (idx < N_NODES_) {
        int rp = blk_off[b] + sh[t] - v;
        row_ptr[idx] = rp;
        cursor[idx]  = rp;
    }
    if (idx == 0) row_ptr[N_NODES_] = N_EDGES_;
}

// ---------------- bucket edges by dst ----------------
__global__ void csr_scatter_kernel(const int* __restrict__ src, const int* __restrict__ dst,
                                   int* __restrict__ cursor, int* __restrict__ csr_src) {
    int i = blockIdx.x * blockDim.x + threadIdx.x;
    if (i >= N_EDGES_) return;
    int d = dst[i];
    int pos = atomicAdd(&cursor[d], 1);
    csr_src[pos] = src[i];
}

// ---------------- W1 [1433][256] f32 -> W1T bf16 [256][1440] (zero-padded) ----------------
__global__ void w1t_kernel(const float* __restrict__ W1, u16* __restrict__ W1T) {
    int gid = blockIdx.x * blockDim.x + threadIdx.x;
    if (gid >= HIDDEN_ * K_PAD_) return;
    int k = gid % K_PAD_, n = gid / K_PAD_;
    float v = (k < N_FEAT_) ? W1[(long)k * HIDDEN_ + n] : 0.f;
    W1T[(long)n * K_PAD_ + k] = f2bf(v);
}

// ---------------- GEMM1 fused cvt: h1s = (x @ W1) * dinv[row]  ----------------
// BM=64, BN=256 (single column pass -> x read exactly once), BK=32.
// 256 threads / 4 waves; wave wv owns rows[0..64) x cols[wv*64, wv*64+64).
// A: f32 x loaded coalesced (per load-instr: 2 rows x 128B contiguous),
//    RNE-converted to bf16 in regs, ds_write_b16 into As (2-way bank alias = free).
// B: bf16 W1T staged via global_load_lds (16B, m97 pattern).
// k >= 1433 reads clamped garbage but W1T is zero there -> contributes 0.
// rows >= 50000 clamp to row 49999; epilogue guard discards them.
__global__ __launch_bounds__(256) void gemm1_fused(const float* __restrict__ X,
                                                   const u16* __restrict__ BT,   // W1T [256][1440] bf16
                                                   const float* __restrict__ dinv,
                                                   u16* __restrict__ C) {        // h1s [50001][256] bf16
    __shared__ u16 As[64 * 32];    // [m][k], 64 B rows, 4 KB
    __shared__ u16 Bs[256 * 32];   // [n][k], 16 KB

    const int tid  = threadIdx.x;
    const int lane = tid & 63;
    const int wv   = tid >> 6;
    const int row0 = blockIdx.x * 64;
    const int wc0  = wv * 64;

    f32x4 acc[4][4] = {};

    // B-staging lane geometry (16 rows per instr)
    const int srow = lane >> 2;
    const int skk  = (lane & 3) * 8;
    // A-staging lane geometry: thread covers (row = ar + 8j, k = ak)
    const int ar = tid >> 5;   // 0..7
    const int ak = tid & 31;
    const int kmax = N_FEAT_ - 1;

    for (int k0 = 0; k0 < K_PAD_; k0 += 32) {
        // B tile: 256x32 bf16, 16 global_load_lds per block (4 per wave)
        #pragma unroll
        for (int j = 0; j < 4; j++) {
            int rbase = j * 64 + wv * 16;
            const u16* g = BT + (long)(rbase + srow) * K_PAD_ + k0 + skk;
            global_to_lds16(g, &Bs[rbase * 32]);
        }
        // A tile: 64x32 f32 -> bf16, reg-staged
        int kcl = min(k0 + ak, kmax);
        float av[8];
        #pragma unroll
        for (int j = 0; j < 8; j++) {
            int rcl = min(row0 + ar + j * 8, N_NODES_ - 1);
            av[j] = X[(long)rcl * N_FEAT_ + kcl];
        }
        #pragma unroll
        for (int j = 0; j < 8; j++)
            As[(ar + j * 8) * 32 + ak] = f2bf(av[j]);
        __syncthreads();

        const int fm = lane & 15;
        const int fq = (lane >> 4) * 8;
        short8 af[4], bf[4];
        #pragma unroll
        for (int mi = 0; mi < 4; mi++)
            af[mi] = *(const short8*)&As[(mi * 16 + fm) * 32 + fq];
        #pragma unroll
        for (int ni = 0; ni < 4; ni++)
            bf[ni] = *(const short8*)&Bs[(wc0 + ni * 16 + fm) * 32 + fq];
        #pragma unroll
        for (int mi = 0; mi < 4; mi++)
            #pragma unroll
            for (int ni = 0; ni < 4; ni++)
                acc[mi][ni] = __builtin_amdgcn_mfma_f32_16x16x32_bf16(af[mi], bf[ni], acc[mi][ni], 0, 0, 0);
        __syncthreads();
    }

    // epilogue: C/D layout col=lane&15, row=(lane>>4)*4+r; scale by dinv[row]
    const int fm = lane & 15;
    const int q4 = (lane >> 4) * 4;
    #pragma unroll
    for (int mi = 0; mi < 4; mi++) {
        #pragma unroll
        for (int r = 0; r < 4; r++) {
            int gm = row0 + mi * 16 + q4 + r;
            if (gm < N_NODES_) {
                float sc = dinv[gm];
                #pragma unroll
                for (int ni = 0; ni < 4; ni++) {
                    int gn = wc0 + ni * 16 + fm;
                    C[(long)gm * HIDDEN_ + gn] = f2bf(acc[mi][ni][r] * sc);
                }
            }
        }
    }
}

// ---------------- fused: agg1 (row-sum of pre-scaled h1s) + bias1 + relu + GEMM2 ----------------
__global__ __launch_bounds__(256) void agg_gemm2_kernel(const u16* __restrict__ h1s,
                                                        const int* __restrict__ row_ptr,
                                                        const int* __restrict__ csr_src,
                                                        const float* __restrict__ dinv,
                                                        const float* __restrict__ b1,
                                                        const float* __restrict__ W2,
                                                        float* __restrict__ h2s) {
    __shared__ float w2s[HIDDEN_ * N_CLASSES_];
    __shared__ float b1s[HIDDEN_];
    int tid = threadIdx.x;
    for (int i = tid; i < HIDDEN_ * N_CLASSES_; i += 256) w2s[i] = W2[i];
    for (int i = tid; i < HIDDEN_; i += 256) b1s[i] = b1[i];
    __syncthreads();

    int wave = tid >> 6;
    int lane = tid & 63;
    int node = blockIdx.x * 4 + wave;
    if (node >= N_NODES_) return;

    int e0 = row_ptr[node], e1 = row_ptr[node + 1];
    float ax = 0.f, ay = 0.f, az = 0.f, aw = 0.f;

    int sL = (e0 + lane < e1) ? csr_src[e0 + lane] : N_NODES_;
    for (int base = e0; base < e1; base += 64) {
        int sCur = sL;
        int nb = base + 64;
        if (nb < e1) sL = (nb + lane < e1) ? csr_src[nb + lane] : N_NODES_;
        int cnt8 = (min(64, e1 - base) + 7) & ~7;
        for (int j = 0; j < cnt8; j += 8) {
            #pragma unroll
            for (int t = 0; t < 8; t++) {
                int s = __shfl(sCur, j + t, 64);
                ushort4 u = ((const ushort4*)(h1s + (long)s * HIDDEN_))[lane];
                ax += bf2f(u.x);
                ay += bf2f(u.y);
                az += bf2f(u.z);
                aw += bf2f(u.w);
            }
        }
    }
    float nd = dinv[node];
    ushort4 su = ((const ushort4*)(h1s + (long)node * HIDDEN_))[lane];
    float xv[4];
    xv[0] = fmaxf((ax + bf2f(su.x)) * nd + b1s[lane * 4 + 0], 0.f);
    xv[1] = fmaxf((ay + bf2f(su.y)) * nd + b1s[lane * 4 + 1], 0.f);
    xv[2] = fmaxf((az + bf2f(su.z)) * nd + b1s[lane * 4 + 2], 0.f);
    xv[3] = fmaxf((aw + bf2f(su.w)) * nd + b1s[lane * 4 + 3], 0.f);

    float p[N_CLASSES_];
    #pragma unroll
    for (int c = 0; c < N_CLASSES_; c++) {
        float a = 0.f;
        #pragma unroll
        for (int i = 0; i < 4; i++)
            a += xv[i] * w2s[(lane * 4 + i) * N_CLASSES_ + c];
        p[c] = a;
    }
    #pragma unroll
    for (int off = 32; off > 0; off >>= 1)
        #pragma unroll
        for (int c = 0; c < N_CLASSES_; c++)
            p[c] += __shfl_down(p[c], off, 64);
    if (lane == 0) {
        #pragma unroll
        for (int c = 0; c < N_CLASSES_; c++)
            h2s[(long)node * 8 + c] = p[c] * nd;   // pre-scaled, stride-8 rows
    }
}

// ---------------- output: row-sum of pre-scaled h2s + self + bias2 ----------------
__global__ void out_kernel(const float* __restrict__ h2s,
                           const int* __restrict__ row_ptr,
                           const int* __restrict__ csr_src,
                           const float* __restrict__ dinv,
                           const float* __restrict__ b2,
                           float* __restrict__ out) {
    long gid = (long)blockIdx.x * blockDim.x + threadIdx.x;
    int node = (int)(gid >> 3);
    int c = (int)(gid & 7);
    if (node >= N_NODES_ || c >= N_CLASSES_) return;
    int e0 = row_ptr[node], e1 = row_ptr[node + 1];
    float acc = 0.f;
    for (int e = e0; e < e1; e += 4) {
        int s0 = csr_src[e];
        int s1 = (e + 1 < e1) ? csr_src[e + 1] : N_NODES_;
        int s2 = (e + 2 < e1) ? csr_src[e + 2] : N_NODES_;
        int s3 = (e + 3 < e1) ? csr_src[e + 3] : N_NODES_;
        float v0 = h2s[(long)s0 * 8 + c];
        float v1 = h2s[(long)s1 * 8 + c];
        float v2 = h2s[(long)s2 * 8 + c];
        float v3 = h2s[(long)s3 * 8 + c];
        acc += (v0 + v1) + (v2 + v3);
    }
    float nd = dinv[node];
    out[(long)node * N_CLASSES_ + c] =
        (acc + h2s[(long)node * 8 + c]) * nd + b2[c];
}

extern "C" void kernel_launch(void* const* d_in, const int* in_sizes, int n_in,
                              void* d_out, int out_size, void* d_ws, size_t ws_size,
                              hipStream_t stream) {
    const float* x   = (const float*)d_in[0];
    const int*   ei  = (const int*)d_in[1];
    const int*   src = ei;
    const int*   dst = ei + N_EDGES_;
    const float* W1  = (const float*)d_in[2];
    const float* b1  = (const float*)d_in[3];
    const float* W2  = (const float*)d_in[4];
    const float* b2  = (const float*)d_in[5];
    float* out = (float*)d_out;

    // workspace layout (256B aligned), ~35 MB total
    char* ws = (char*)d_ws;
    size_t off = 0;
    auto alloc = [&](size_t bytes) { void* p = ws + off; off = (off + bytes + 255) & ~(size_t)255; return p; };
    u16*   h1s     = (u16*)alloc((size_t)(N_NODES_ + 1) * HIDDEN_ * 2);   // 25.6 MB (+pad row)
    u16*   w1t     = (u16*)alloc((size_t)HIDDEN_ * K_PAD_ * 2);           // 0.74 MB
    float* h2s     = (float*)alloc((size_t)(N_NODES_ + 1) * 8 * 4);       // 1.6 MB (+pad row)
    int*   deg     = (int*)alloc((size_t)N_NODES_ * 4);
    float* dinv    = (float*)alloc((size_t)N_NODES_ * 4);
    int*   row_ptr = (int*)alloc((size_t)(N_NODES_ + 1) * 4);
    int*   cursor  = (int*)alloc((size_t)N_NODES_ * 4);
    int*   csr_src = (int*)alloc((size_t)N_EDGES_ * 4);                   // 6.4 MB
    int*   partial = (int*)alloc((size_t)NPART_ * 4);
    int*   blk_off = (int*)alloc((size_t)NPART_ * 4);

    hipMemsetAsync(deg, 0, (size_t)N_NODES_ * 4, stream);
    hipMemsetAsync(h1s + (size_t)N_NODES_ * HIDDEN_, 0, HIDDEN_ * 2, stream);  // zero pad row
    hipMemsetAsync(h2s + (size_t)N_NODES_ * 8, 0, 8 * 4, stream);              // zero pad row

    deg_kernel<<<(N_EDGES_ + 255) / 256, 256, 0, stream>>>(dst, deg);
    dinv_kernel<<<(N_NODES_ + 255) / 256, 256, 0, stream>>>(deg, dinv);
    scan1_kernel<<<NPART_, 256, 0, stream>>>(deg, partial);
    scan2_kernel<<<1, 256, 0, stream>>>(partial, blk_off);
    scan3_kernel<<<NPART_, 256, 0, stream>>>(deg, blk_off, row_ptr, cursor);
    csr_scatter_kernel<<<(N_EDGES_ + 255) / 256, 256, 0, stream>>>(src, dst, cursor, csr_src);

    w1t_kernel<<<(HIDDEN_ * K_PAD_ + 255) / 256, 256, 0, stream>>>(W1, w1t);

    gemm1_fused<<<NB_ROWS_ / 64, 256, 0, stream>>>(x, w1t, dinv, h1s);

    agg_gemm2_kernel<<<(N_NODES_ + 3) / 4, 256, 0, stream>>>(h1s, row_ptr, csr_src, dinv, b1, W2, h2s);

    long out_threads = (long)N_NODES_ * 8;
    out_kernel<<<(unsigned)((out_threads + 255) / 256), 256, 0, stream>>>(h2s, row_ptr, csr_src, dinv, b2, out);
}